// Round 2
// baseline (29.444 us; speedup 1.0000x reference)
//
#include <hip/hip_runtime.h>
#include <math.h>

#define BB 4
#define NN 64
#define TT 80
#define DD 6
#define KK 5
#define BUFFER_DIST 0.2f
#define DECAY 0.9f
#define CHUNKS 4   // blocks per (b,t); each block covers 512 of the 2048 pair-slots

__global__ __launch_bounds__(256) void collision_kernel(
    const float* __restrict__ Y,
    const float* __restrict__ length,
    const float* __restrict__ width,
    float* __restrict__ out)
{
    const int blk   = blockIdx.x;      // (b*TT + t)*CHUNKS + chunk
    const int bt    = blk >> 2;
    const int chunk = blk & 3;
    const int b = bt / TT;
    const int t = bt - b * TT;
    const int tid = threadIdx.x;

    __shared__ float2 w[KK][NN];   // disk centers
    __shared__ float rad[NN];

    if (tid < NN) {
        const int n = tid;
        const float* y = Y + (((size_t)(b * NN + n) * TT + t) * DD);
        const float px  = y[0];
        const float py  = y[1];
        const float yaw = y[4];
        const float c = cosf(yaw);
        const float s = sinf(yaw);
        const float L = length[b * NN + n];
        const float W = width[b * NN + n];
        const float ar = 0.5f * W;
        rad[n] = ar;
        const float cmin = -(0.5f * L) + ar;
        const float cmax =  (0.5f * L) - ar;
        const float span = cmax - cmin;
        #pragma unroll
        for (int k = 0; k < KK; ++k) {
            const float frac = (float)k / (float)(KK - 1);
            const float cx = cmin + span * frac;
            w[k][n] = make_float2(fmaf(cx, c, px), fmaf(-cx, s, py));
        }
    }
    __syncthreads();

    float sum = 0.0f;
    // Triangle fold: slots p in [0,2048), r=p>>6 in [0,32), c=p&63.
    //   c>r  -> pair (r, c)
    //   c<r  -> pair (63-r, 63-c)
    //   c==r -> diagonal (i==j, contributes 0)
    // Covers each unordered pair i<j exactly once; full sum = 2x this.
    #pragma unroll
    for (int iter = 0; iter < 2; ++iter) {
        const int p = chunk * 512 + iter * 256 + tid;
        const int r = p >> 6;
        const int c = p & 63;
        const bool flip = (c <= r);
        const int i = flip ? (NN - 1 - r) : r;
        const int j = flip ? (NN - 1 - c) : c;

        float2 wi[KK];
        #pragma unroll
        for (int k = 0; k < KK; ++k) wi[k] = w[k][i];

        float mind2 = 3.4e38f;
        #pragma unroll
        for (int l = 0; l < KK; ++l) {
            const float2 wj = w[l][j];
            #pragma unroll
            for (int k = 0; k < KK; ++k) {
                const float dx = wi[k].x - wj.x;
                const float dy = wi[k].y - wj.y;
                const float d2 = fmaf(dx, dx, dy * dy);
                mind2 = fminf(mind2, d2);
            }
        }
        const float dist = (mind2 > 1e-12f) ? sqrtf(mind2) : 0.0f;
        const float pd = rad[i] + rad[j] + BUFFER_DIST;
        const float pen = 1.0f - dist / pd;
        const bool valid = (i != j) && (dist <= pd);
        sum += valid ? pen : 0.0f;
    }

    // wave reduce (64 lanes), then cross-wave via LDS
    #pragma unroll
    for (int off = 32; off > 0; off >>= 1)
        sum += __shfl_down(sum, off, 64);
    __shared__ float wsum[4];
    const int wave = tid >> 6;
    const int lane = tid & 63;
    if (lane == 0) wsum[wave] = sum;
    __syncthreads();
    if (tid == 0) {
        const float tot = wsum[0] + wsum[1] + wsum[2] + wsum[3];
        // exp_w[t] = 0.9^t / sum_u 0.9^u (geometric closed form); x2 for triangle
        const float denom = (1.0f - powf(DECAY, (float)TT)) / (1.0f - DECAY);
        const float wgt = powf(DECAY, (float)t) / denom;
        atomicAdd(out, tot * wgt * (2.0f / (float)(BB * NN * TT)));
    }
}

extern "C" void kernel_launch(void* const* d_in, const int* in_sizes, int n_in,
                              void* d_out, int out_size, void* d_ws, size_t ws_size,
                              hipStream_t stream) {
    const float* Y      = (const float*)d_in[0];
    const float* length = (const float*)d_in[1];
    const float* width  = (const float*)d_in[2];
    float* out = (float*)d_out;

    hipMemsetAsync(out, 0, sizeof(float) * (size_t)out_size, stream);
    collision_kernel<<<BB * TT * CHUNKS, 256, 0, stream>>>(Y, length, width, out);
}

// Round 3
// 12.150 us; speedup vs baseline: 2.4234x; 2.4234x over previous
//
#include <hip/hip_runtime.h>
#include <math.h>

#define BB 4
#define NN 64
#define TT 80
#define DD 6
#define KK 5
#define BUFFER_DIST 0.2f
#define DECAY 0.9f
#define CHUNKS 4   // blocks per (b,t); each covers 512 of the 2048 pair-slots
#define NPART (BB * TT * CHUNKS)   // 1280 partials

__global__ __launch_bounds__(256) void collision_kernel(
    const float* __restrict__ Y,
    const float* __restrict__ length,
    const float* __restrict__ width,
    float* __restrict__ partial) // [NPART], unweighted per-chunk sums
{
    const int blk   = blockIdx.x;      // (b*TT + t)*CHUNKS + chunk
    const int bt    = blk >> 2;
    const int chunk = blk & 3;
    const int b = bt / TT;
    const int t = bt - b * TT;
    const int tid = threadIdx.x;

    __shared__ float2 w[KK][NN];   // disk centers
    __shared__ float rad[NN];

    if (tid < NN) {
        const int n = tid;
        const float* y = Y + (((size_t)(b * NN + n) * TT + t) * DD);
        const float px  = y[0];
        const float py  = y[1];
        const float yaw = y[4];
        const float c = cosf(yaw);
        const float s = sinf(yaw);
        const float L = length[b * NN + n];
        const float W = width[b * NN + n];
        const float ar = 0.5f * W;
        rad[n] = ar;
        const float cmin = -(0.5f * L) + ar;
        const float cmax =  (0.5f * L) - ar;
        const float span = cmax - cmin;
        #pragma unroll
        for (int k = 0; k < KK; ++k) {
            const float frac = (float)k / (float)(KK - 1);
            const float cx = cmin + span * frac;
            w[k][n] = make_float2(fmaf(cx, c, px), fmaf(-cx, s, py));
        }
    }
    __syncthreads();

    float sum = 0.0f;
    // Triangle fold: slots p in [0,2048), r=p>>6 in [0,32), c=p&63.
    //   c>r -> (r,c); c<r -> (63-r,63-c); c==r -> i==j (contributes 0).
    // Each unordered pair i<j covered exactly once; full sum = 2x this.
    #pragma unroll
    for (int iter = 0; iter < 2; ++iter) {
        const int p = chunk * 512 + iter * 256 + tid;
        const int r = p >> 6;
        const int c = p & 63;
        const bool flip = (c <= r);
        const int i = flip ? (NN - 1 - r) : r;
        const int j = flip ? (NN - 1 - c) : c;

        float2 wi[KK];
        #pragma unroll
        for (int k = 0; k < KK; ++k) wi[k] = w[k][i];

        float mind2 = 3.4e38f;
        #pragma unroll
        for (int l = 0; l < KK; ++l) {
            const float2 wj = w[l][j];
            #pragma unroll
            for (int k = 0; k < KK; ++k) {
                const float dx = wi[k].x - wj.x;
                const float dy = wi[k].y - wj.y;
                const float d2 = fmaf(dx, dx, dy * dy);
                mind2 = fminf(mind2, d2);
            }
        }
        const float dist = (mind2 > 1e-12f) ? sqrtf(mind2) : 0.0f;
        const float pd = rad[i] + rad[j] + BUFFER_DIST;
        const float pen = 1.0f - dist / pd;
        const bool valid = (i != j) && (dist <= pd);
        sum += valid ? pen : 0.0f;
    }

    // wave reduce (64 lanes), then cross-wave via LDS
    #pragma unroll
    for (int off = 32; off > 0; off >>= 1)
        sum += __shfl_down(sum, off, 64);
    __shared__ float wsum[4];
    const int wave = tid >> 6;
    const int lane = tid & 63;
    if (lane == 0) wsum[wave] = sum;
    __syncthreads();
    if (tid == 0)
        partial[blk] = wsum[0] + wsum[1] + wsum[2] + wsum[3];
}

__global__ __launch_bounds__(256) void reduce_kernel(
    const float* __restrict__ partial, float* __restrict__ out)
{
    const int tid = threadIdx.x;
    float s = 0.0f;
    #pragma unroll
    for (int it = 0; it < NPART / 256; ++it) {
        const int idx = it * 256 + tid;     // = (b*TT + t)*CHUNKS + chunk
        const int bt = idx >> 2;
        const int t = bt % TT;
        s = fmaf(partial[idx], powf(DECAY, (float)t), s);
    }
    #pragma unroll
    for (int off = 32; off > 0; off >>= 1)
        s += __shfl_down(s, off, 64);
    __shared__ float wsum[4];
    const int wave = tid >> 6;
    const int lane = tid & 63;
    if (lane == 0) wsum[wave] = s;
    __syncthreads();
    if (tid == 0) {
        const float denom = (1.0f - powf(DECAY, (float)TT)) * 10.0f; // /(1-0.9)
        const float scale = 2.0f / ((float)(BB * NN * TT) * denom);
        out[0] = (wsum[0] + wsum[1] + wsum[2] + wsum[3]) * scale;
    }
}

extern "C" void kernel_launch(void* const* d_in, const int* in_sizes, int n_in,
                              void* d_out, int out_size, void* d_ws, size_t ws_size,
                              hipStream_t stream) {
    const float* Y      = (const float*)d_in[0];
    const float* length = (const float*)d_in[1];
    const float* width  = (const float*)d_in[2];
    float* out = (float*)d_out;
    float* partial = (float*)d_ws;   // NPART*4 = 5120 bytes

    collision_kernel<<<NPART, 256, 0, stream>>>(Y, length, width, partial);
    reduce_kernel<<<1, 256, 0, stream>>>(partial, out);
}